// Round 13
// baseline (420.779 us; speedup 1.0000x reference)
//
#include <hip/hip_runtime.h>
#include <hip/hip_bf16.h>
#include <stdint.h>

typedef __bf16 bf16_t;
typedef __bf16 bf16x8 __attribute__((ext_vector_type(8)));
typedef __bf16 bf16x4 __attribute__((ext_vector_type(4)));
typedef float f32x4 __attribute__((ext_vector_type(4)));

#define NROW 6000           // rows of each graph
#define HID 256
#define NHEAD 4
#define HD 64
#define ATT_SCALE 0.125f    // HEAD_DIM^-0.5 = 1/8
#define MTOT 12000          // both graphs concatenated
#define CAP 128             // ELL capacity; Binom(6000,0.01) mean 60 sd 7.7

#define SCANB 1500          // 4 waves/block, 1 wave per row -> 6000 rows
#define ZEROB 26            // 26*256 = 6656 >= 6512 ints (ccur + Vsum)
#define PROJB (188 * 12)    // 2256

// f32 row -> bf16x8 fragment
__device__ inline bf16x8 cvt8(const float* __restrict__ p)
{
    f32x4 x0 = *(const f32x4*)p;
    f32x4 x1 = *(const f32x4*)(p + 4);
    bf16x8 r;
#pragma unroll
    for (int i = 0; i < 4; ++i) { r[i] = (bf16_t)x0[i]; r[4 + i] = (bf16_t)x1[i]; }
    return r;
}

// ============ K1: rowwise atomic-free scan ∥ zero ∥ QKV projection ===========
// scan: one wave per align-matrix row (375 chunks of 16 f32 = 6 iters of 64
// lanes); running in-register offset, no atomics, lists sorted.
// proj: MFMA GEMM, f32 weights converted inline (no canon dependency).
__global__ __launch_bounds__(256)
void k1_scan_proj(const float* __restrict__ am,
                  int* __restrict__ rcnt, int* __restrict__ csr,
                  int* __restrict__ zbase,           // ccur|Vsum region
                  const float* __restrict__ e1, const float* __restrict__ e2,
                  const float* __restrict__ wq, const float* __restrict__ wk,
                  const float* __restrict__ wv,
                  const float* __restrict__ bq, const float* __restrict__ bk,
                  const float* __restrict__ bv,
                  bf16_t* __restrict__ Q, bf16_t* __restrict__ Kf, bf16_t* __restrict__ V)
{
    int lane = threadIdx.x & 63;
    int wave = threadIdx.x >> 6;

    if (blockIdx.x < SCANB) {
        // ---------------- scan path: one wave per row ----------------
        int n = blockIdx.x * 4 + wave;              // row < 6000
        const uint4* rowp = (const uint4*)(am + (size_t)n * NROW); // 375*4 uint4

        unsigned int masks[6];
#pragma unroll
        for (int i = 0; i < 6; ++i) {
            int c = i * 64 + lane;                  // chunk index
            unsigned int m = 0;
            if (c < 375) {
                const uint4* p4 = rowp + c * 4;
                uint4 u0 = p4[0], u1 = p4[1], u2 = p4[2], u3 = p4[3];
                unsigned int any = u0.x | u0.y | u0.z | u0.w | u1.x | u1.y | u1.z | u1.w
                                 | u2.x | u2.y | u2.z | u2.w | u3.x | u3.y | u3.z | u3.w;
                if (any) {
                    unsigned int w[16] = {u0.x, u0.y, u0.z, u0.w, u1.x, u1.y, u1.z, u1.w,
                                          u2.x, u2.y, u2.z, u2.w, u3.x, u3.y, u3.z, u3.w};
#pragma unroll
                    for (int p = 0; p < 16; ++p)
                        if (w[p]) m |= 1u << p;
                }
            }
            masks[i] = m;
        }

        int* dst = csr + (size_t)n * CAP;
        int base = 0;
#pragma unroll
        for (int i = 0; i < 6; ++i) {
            unsigned int m = masks[i];
            int c = __popc(m);
            int p = c;
#pragma unroll
            for (int off = 1; off < 64; off <<= 1) {
                int t = __shfl_up(p, off);
                if (lane >= off) p += t;
            }
            int excl  = p - c;
            int total = __shfl(p, 63);
            if (m) {
                int col0 = (i * 64 + lane) * 16;
                int w = 0;
#pragma unroll
                for (int pb = 0; pb < 16; ++pb) {
                    if (m & (1u << pb)) {
                        int idx = base + excl + (w++);
                        if (idx < CAP) dst[idx] = col0 + pb;
                    }
                }
            }
            base += total;
        }
        if (lane == 0) rcnt[n] = base;
        return;
    }

    if (blockIdx.x < SCANB + ZEROB) {
        // ---------------- zero path: ccur (6000) + Vsum (512) ----------------
        int i = (blockIdx.x - SCANB) * 256 + threadIdx.x;
        if (i < NROW + 2 * HID) zbase[i] = 0;
        return;
    }

    // ---------------- projection: [12000,256] @ {Wq,Wk,Wv}^T + bias ----------
    int bx   = blockIdx.x - (SCANB + ZEROB);
    int m0   = (bx % 188) * 64;
    int n0   = (bx / 188) * 64;      // output col in [0,768)
    int r16  = lane & 15;
    int quad = lane >> 4;

    int sel = n0 >> 8;               // 0=Q, 1=K, 2=V
    int jb  = n0 & 255;
    const float* wsrc = (sel == 0) ? wq : (sel == 1) ? wk : wv;
    const float* bias = (sel == 0) ? bq : (sel == 1) ? bk : bv;

    int arow = m0 + wave * 16 + r16;
    int rr   = arow < MTOT ? arow : MTOT - 1;
    const float* asrc = (rr < NROW) ? (e1 + (size_t)rr * HID)
                                    : (e2 + (size_t)(rr - NROW) * HID);

    f32x4 acc0 = {0,0,0,0}, acc1 = {0,0,0,0}, acc2 = {0,0,0,0}, acc3 = {0,0,0,0};
#pragma unroll
    for (int kk = 0; kk < HID; kk += 32) {
        bf16x8 a = cvt8(asrc + kk + quad * 8);
        const float* b0 = wsrc + (size_t)(jb + r16) * HID + kk + quad * 8;
        bf16x8 f0 = cvt8(b0);
        bf16x8 f1 = cvt8(b0 + 16 * HID);
        bf16x8 f2 = cvt8(b0 + 32 * HID);
        bf16x8 f3 = cvt8(b0 + 48 * HID);
        acc0 = __builtin_amdgcn_mfma_f32_16x16x32_bf16(a, f0, acc0, 0, 0, 0);
        acc1 = __builtin_amdgcn_mfma_f32_16x16x32_bf16(a, f1, acc1, 0, 0, 0);
        acc2 = __builtin_amdgcn_mfma_f32_16x16x32_bf16(a, f2, acc2, 0, 0, 0);
        acc3 = __builtin_amdgcn_mfma_f32_16x16x32_bf16(a, f3, acc3, 0, 0, 0);
    }
    f32x4 accs[4] = {acc0, acc1, acc2, acc3};
    bf16_t* dst = (sel == 0) ? Q : (sel == 1) ? Kf : V;
    int rbase = m0 + wave * 16 + quad * 4;
#pragma unroll
    for (int nt = 0; nt < 4; ++nt) {
        int j = jb + nt * 16 + r16;
        float bb = bias[j];
#pragma unroll
        for (int rg = 0; rg < 4; ++rg) {
            int r = rbase + rg;
            if (r < MTOT)
                dst[(size_t)r * HID + j] = (bf16_t)(accs[nt][rg] + bb);
        }
    }
}

// ============ K2: Kbar + Vsum  ∥  CSC-from-CSR scatter =======================
// Blocks [0,3000): Kbar. [3000,3048): Vsum. [3048,6048): CSC.
__global__ __launch_bounds__(256)
void k2_aux(const bf16_t* __restrict__ Kf, const bf16_t* __restrict__ V,
            bf16_t* __restrict__ Kbar, float* __restrict__ Vsum,
            const int* __restrict__ rcnt, const int* __restrict__ csr,
            int* __restrict__ ccur, int* __restrict__ csc)
{
    int b = blockIdx.x;
    if (b < 3000) {                       // Kbar: 12000*64 outputs
        int id = b * 256 + threadIdx.x;
        int m = id >> 6, d = id & 63;
        const bf16_t* kr = Kf + (size_t)m * HID + d;
        Kbar[id] = (bf16_t)(0.25f * ((float)kr[0] + (float)kr[64] +
                                     (float)kr[128] + (float)kr[192]));
    } else if (b < 3048) {                // Vsum: 2 graphs x 24 segments of 250
        int idx = b - 3000;
        int g = idx / 24;
        int seg = idx - g * 24;
        int j = threadIdx.x;
        const bf16_t* base = V + ((size_t)(g * NROW + seg * 250)) * HID + j;
        float s = 0.f;
        for (int m = 0; m < 250; ++m) s += (float)base[(size_t)m * HID];
        atomicAdd(Vsum + g * HID + j, s);
    } else {                              // CSC scatter
        int tid = (b - 3048) * 256 + threadIdx.x;   // n*CAP + j
        int n = tid >> 7, j = tid & (CAP - 1);
        if (n >= NROW) return;
        int cnt = rcnt[n]; if (cnt > CAP) cnt = CAP;
        if (j >= cnt) return;
        int m = csr[(size_t)n * CAP + j];
        int slot = atomicAdd(ccur + m, 1);
        if (slot < CAP) csc[(size_t)m * CAP + slot] = n;
    }
}

// ---------------- sparse-corrected attention (both directions) ---------------
// Exact softmax over 6000 kv entries: masked-out entries share weight e^-M/Z.
// Phase 1 on MFMA: scores = Kbar[rows]·q^T, A-fragments gathered directly from
// global (16B/lane, native A layout), B = q row (bf16, LDS), heads in C cols.
__global__ __launch_bounds__(256)
void attn_kernel(const bf16_t* __restrict__ Q, const bf16_t* __restrict__ Kbar,
                 const bf16_t* __restrict__ V, const float* __restrict__ Vsum,
                 const int* __restrict__ rcnt, const int* __restrict__ ccnt,
                 const int* __restrict__ csr, const int* __restrict__ csc,
                 bf16_t* __restrict__ att)
{
    __shared__ __align__(16) bf16_t qsb[HID];      // 0.5 KB, q row in bf16
    __shared__ int   ml[CAP];                      // 0.5 KB
    __shared__ float sc[CAP * 5];                  // 2.5 KB, [j][head] stride 5
    __shared__ float w0s[NHEAD];
    __shared__ float red[4 * HID];                 // 4 KB cross-wave reduction

    int dir = blockIdx.y;
    int n   = blockIdx.x;
    int t   = threadIdx.x;
    int wave = t >> 6, lane = t & 63;

    size_t qrow = (size_t)(dir ? NROW + n : n);
    const bf16_t* kb_base = Kbar + (dir ? 0 : (size_t)NROW * HD);
    const bf16_t* v_base  = V    + (dir ? 0 : (size_t)NROW * HID);
    const float*  vs      = Vsum + (dir ? 0 : HID);
    const int*    lst     = (dir ? csc : csr) + (size_t)n * CAP;
    int cnt = (dir ? ccnt : rcnt)[n];
    if (cnt > CAP) cnt = CAP;

    qsb[t] = Q[qrow * HID + t];
    for (int j = t; j < cnt; j += 256) ml[j] = lst[j];
    __syncthreads();

    int m16  = lane & 15;
    int quad = lane >> 4;

    // phase 1 (MFMA): per 16-j tile, scores[j][head] = SCALE * Kbar[mj]·q_head
    {
        bf16x8 b0, b1;
        if (m16 < NHEAD) {
            b0 = *(const bf16x8*)(qsb + m16 * HD + 0  + quad * 8);
            b1 = *(const bf16x8*)(qsb + m16 * HD + 32 + quad * 8);
        } else {
            b0 = (bf16x8)(bf16_t)0.f;
            b1 = (bf16x8)(bf16_t)0.f;
        }
        for (int jt = wave; jt * 16 < cnt; jt += 4) {
            int j  = jt * 16 + m16;
            int jj = j < cnt ? j : cnt - 1;           // clamp (cnt>0 here)
            int row = ml[jj];
            const bf16_t* ap = kb_base + (size_t)row * HD + quad * 8;
            bf16x8 a0 = *(const bf16x8*)(ap);
            bf16x8 a1 = *(const bf16x8*)(ap + 32);
            f32x4 acc = {0, 0, 0, 0};
            acc = __builtin_amdgcn_mfma_f32_16x16x32_bf16(a0, b0, acc, 0, 0, 0);
            acc = __builtin_amdgcn_mfma_f32_16x16x32_bf16(a1, b1, acc, 0, 0, 0);
            // C layout: col = lane&15 (head), row = quad*4 + rg (j within tile)
            if (m16 < NHEAD) {
#pragma unroll
                for (int rg = 0; rg < 4; ++rg) {
                    int jw = jt * 16 + quad * 4 + rg;
                    if (jw < cnt) sc[jw * 5 + m16] = acc[rg] * ATT_SCALE;
                }
            }
        }
    }
    __syncthreads();

    // phase 2: per-head exact softmax stats; wave `head` owns head `head`
    {
        int head = wave;
        float M = 0.0f;              // zero-score baseline always present
        for (int j = lane; j < cnt; j += 64) M = fmaxf(M, sc[j * 5 + head]);
        for (int off = 32; off; off >>= 1) M = fmaxf(M, __shfl_xor(M, off));
        float e0 = __expf(-M);
        float e[2]; int k = 0;
        float S = 0.f;
        for (int j = lane; j < cnt; j += 64, ++k) { e[k] = __expf(sc[j * 5 + head] - M); S += e[k]; }
        for (int off = 32; off; off >>= 1) S += __shfl_xor(S, off);
        float Z = S + (float)(NROW - cnt) * e0;
        float invZ = 1.0f / Z;
        k = 0;
        for (int j = lane; j < cnt; j += 64, ++k) sc[j * 5 + head] = (e[k] - e0) * invZ;
        if (lane == 0) w0s[head] = e0 * invZ;
    }
    __syncthreads();

    // phase 3: wave w handles j = w, w+4, ...; lane covers (h3, 4 dims).
    // 4-deep unroll keeps 4 V-row gathers in flight (L2-latency bound).
    int h3 = lane >> 4;
    int dq = lane & 15;
    int colb = h3 * HD + dq * 4;
    float a0 = 0.f, a1 = 0.f, a2 = 0.f, a3 = 0.f;
    {
        int j = wave;
        for (; j + 12 < cnt; j += 16) {
            int   m0 = ml[j];            int   m1 = ml[j + 4];
            int   m2 = ml[j + 8];        int   m3 = ml[j + 12];
            float c0 = sc[j * 5 + h3];   float c1 = sc[(j + 4) * 5 + h3];
            float c2 = sc[(j + 8) * 5 + h3]; float c3 = sc[(j + 12) * 5 + h3];
            bf16x4 r0 = *(const bf16x4*)(v_base + (size_t)m0 * HID + colb);
            bf16x4 r1 = *(const bf16x4*)(v_base + (size_t)m1 * HID + colb);
            bf16x4 r2 = *(const bf16x4*)(v_base + (size_t)m2 * HID + colb);
            bf16x4 r3 = *(const bf16x4*)(v_base + (size_t)m3 * HID + colb);
            a0 += c0 * (float)r0[0] + c1 * (float)r1[0] + c2 * (float)r2[0] + c3 * (float)r3[0];
            a1 += c0 * (float)r0[1] + c1 * (float)r1[1] + c2 * (float)r2[1] + c3 * (float)r3[1];
            a2 += c0 * (float)r0[2] + c1 * (float)r1[2] + c2 * (float)r2[2] + c3 * (float)r3[2];
            a3 += c0 * (float)r0[3] + c1 * (float)r1[3] + c2 * (float)r2[3] + c3 * (float)r3[3];
        }
        for (; j < cnt; j += 4) {
            int   m0 = ml[j];
            float c0 = sc[j * 5 + h3];
            bf16x4 r0 = *(const bf16x4*)(v_base + (size_t)m0 * HID + colb);
            a0 += c0 * (float)r0[0];
            a1 += c0 * (float)r0[1];
            a2 += c0 * (float)r0[2];
            a3 += c0 * (float)r0[3];
        }
    }
    red[wave * 256 + colb + 0] = a0;
    red[wave * 256 + colb + 1] = a1;
    red[wave * 256 + colb + 2] = a2;
    red[wave * 256 + colb + 3] = a3;
    __syncthreads();
    float tot = red[t] + red[256 + t] + red[512 + t] + red[768 + t]
              + w0s[t >> 6] * vs[t];
    att[qrow * HID + t] = (bf16_t)tot;
}

// ---------------- final projection + residual (f32 Wo inline-cvt, f32 out) ---
__global__ __launch_bounds__(256)
void proj_out_kernel(const bf16_t* __restrict__ att, const float* __restrict__ wo,
                     const float* __restrict__ bo,
                     const float* __restrict__ e1, const float* __restrict__ e2,
                     float* __restrict__ out)
{
    int m0   = blockIdx.x * 64;
    int n0   = blockIdx.y * 64;      // in [0,256)
    int wave = threadIdx.x >> 6;
    int lane = threadIdx.x & 63;
    int r16  = lane & 15;
    int quad = lane >> 4;

    int arow = m0 + wave * 16 + r16;
    int rr   = arow < MTOT ? arow : MTOT - 1;
    const bf16_t* asrc = att + (size_t)rr * HID;

    f32x4 acc0 = {0,0,0,0}, acc1 = {0,0,0,0}, acc2 = {0,0,0,0}, acc3 = {0,0,0,0};
#pragma unroll
    for (int kk = 0; kk < HID; kk += 32) {
        bf16x8 a = *(const bf16x8*)(asrc + kk + quad * 8);
        const float* b0 = wo + (size_t)(n0 + r16) * HID + kk + quad * 8;
        bf16x8 f0 = cvt8(b0);
        bf16x8 f1 = cvt8(b0 + 16 * HID);
        bf16x8 f2 = cvt8(b0 + 32 * HID);
        bf16x8 f3 = cvt8(b0 + 48 * HID);
        acc0 = __builtin_amdgcn_mfma_f32_16x16x32_bf16(a, f0, acc0, 0, 0, 0);
        acc1 = __builtin_amdgcn_mfma_f32_16x16x32_bf16(a, f1, acc1, 0, 0, 0);
        acc2 = __builtin_amdgcn_mfma_f32_16x16x32_bf16(a, f2, acc2, 0, 0, 0);
        acc3 = __builtin_amdgcn_mfma_f32_16x16x32_bf16(a, f3, acc3, 0, 0, 0);
    }
    f32x4 accs[4] = {acc0, acc1, acc2, acc3};
    int rbase = m0 + wave * 16 + quad * 4;
#pragma unroll
    for (int nt = 0; nt < 4; ++nt) {
        int j = n0 + nt * 16 + r16;
        float bb = bo[j];
#pragma unroll
        for (int rg = 0; rg < 4; ++rg) {
            int r = rbase + rg;
            if (r < MTOT) {
                const float* emb = (r < NROW) ? (e1 + (size_t)r * HID)
                                              : (e2 + (size_t)(r - NROW) * HID);
                float v = accs[nt][rg] + bb + emb[j];
                out[(size_t)r * HID + j] = v;        // f32 out; concat row r -> r*256
            }
        }
    }
}

// ---------------- host launcher ----------------------------------------------
extern "C" void kernel_launch(void* const* d_in, const int* in_sizes, int n_in,
                              void* d_out, int out_size, void* d_ws, size_t ws_size,
                              hipStream_t stream)
{
    const float* e1 = (const float*)d_in[0];
    const float* e2 = (const float*)d_in[1];
    const float* am = (const float*)d_in[2];
    const float* wq = (const float*)d_in[3];
    const float* bq = (const float*)d_in[4];
    const float* wk = (const float*)d_in[5];
    const float* bk = (const float*)d_in[6];
    const float* wv = (const float*)d_in[7];
    const float* bv = (const float*)d_in[8];
    const float* wo = (const float*)d_in[9];
    const float* bo = (const float*)d_in[10];
    float* out = (float*)d_out;

    size_t off = 0;
    char* base = (char*)d_ws;
    auto alloc = [&](size_t bytes) -> void* {
        void* p = base + off;
        off += (bytes + 255) & ~(size_t)255;
        return p;
    };
    bf16_t* Q    = (bf16_t*)alloc((size_t)MTOT * HID * 2);
    bf16_t* Kf   = (bf16_t*)alloc((size_t)MTOT * HID * 2);
    bf16_t* V    = (bf16_t*)alloc((size_t)MTOT * HID * 2);
    bf16_t* Kbar = (bf16_t*)alloc((size_t)MTOT * HD * 2);
    bf16_t* att  = (bf16_t*)alloc((size_t)MTOT * HID * 2);
    int*    csr  = (int*)   alloc((size_t)NROW * CAP * 4);
    int*    csc  = (int*)   alloc((size_t)NROW * CAP * 4);
    int*    rcnt = (int*)   alloc(NROW * 4);    // written by K1 scan (no zeroing)
    // zeroed by K1 zero-blocks: ccur | Vsum (contiguous, 6512 ints)
    int*    ccur = (int*)   alloc(NROW * 4);
    float*  Vsum = (float*) alloc(2 * HID * 4);

    // K1: rowwise atomic-free scan ∥ zero(ccur,Vsum) ∥ QKV projection
    k1_scan_proj<<<SCANB + ZEROB + PROJB, 256, 0, stream>>>(
        am, rcnt, csr, ccur, e1, e2, wq, wk, wv, bq, bk, bv, Q, Kf, V);

    // K2: Kbar + Vsum ∥ CSC scatter
    k2_aux<<<6048, 256, 0, stream>>>(Kf, V, Kbar, Vsum, rcnt, csr, ccur, csc);

    // K3: attention, both directions
    attn_kernel<<<dim3(NROW, 2), 256, 0, stream>>>(
        Q, Kbar, V, Vsum, rcnt, ccur, csr, csc, att);

    // K4: final projection + residual (f32 output)
    proj_out_kernel<<<dim3(188, 4), 256, 0, stream>>>(att, wo, bo, e1, e2, out);
}

// Round 14
// 355.071 us; speedup vs baseline: 1.1851x; 1.1851x over previous
//
#include <hip/hip_runtime.h>
#include <hip/hip_bf16.h>
#include <stdint.h>

typedef __bf16 bf16_t;
typedef __bf16 bf16x8 __attribute__((ext_vector_type(8)));
typedef __bf16 bf16x4 __attribute__((ext_vector_type(4)));
typedef float f32x4 __attribute__((ext_vector_type(4)));

#define NROW 6000           // rows of each graph
#define HID 256
#define NHEAD 4
#define HD 64
#define ATT_SCALE 0.125f    // HEAD_DIM^-0.5 = 1/8
#define MTOT 12000          // both graphs concatenated
#define CAP 128             // ELL capacity; Binom(6000,0.01) mean 60 sd 7.7
#define NCH16 2250000       // 6000*6000/16 ; 375 chunks of 16 f32 per row exactly

#define SCAN_BLOCKS  ((NCH16 + 255) / 256)      // 8790
#define PROJ_BLOCKS  (188 * 12)                 // 2256
#define WSTR 264                                // LDS weight row stride (pad vs banks)

// f32 ptr -> bf16x8 fragment
__device__ inline bf16x8 cvt8(const float* __restrict__ p)
{
    f32x4 x0 = *(const f32x4*)p;
    f32x4 x1 = *(const f32x4*)(p + 4);
    bf16x8 r;
#pragma unroll
    for (int i = 0; i < 4; ++i) { r[i] = (bf16_t)x0[i]; r[4 + i] = (bf16_t)x1[i]; }
    return r;
}

// ============ K1: QKV projection (2-stage 32-row LDS weights) ∥ align scan ===
// 16.9 KB LDS (was 33.8) -> ~2x resident blocks; scan latency hidden better.
__global__ __launch_bounds__(256)
void k1_proj_scan(const float* __restrict__ e1, const float* __restrict__ e2,
                  const float* __restrict__ wq, const float* __restrict__ wk,
                  const float* __restrict__ wv,
                  const float* __restrict__ bq, const float* __restrict__ bk,
                  const float* __restrict__ bv,
                  bf16_t* __restrict__ Q, bf16_t* __restrict__ Kf, bf16_t* __restrict__ V,
                  const float* __restrict__ am,
                  int* __restrict__ rcur,          // [NROW] pre-zeroed
                  int* __restrict__ csr)           // [NROW*CAP]
{
    __shared__ bf16_t lds_w[32 * WSTR];            // 16.9 KB

    if (blockIdx.x < PROJ_BLOCKS) {
        // ---- projection: [12000,256] @ {Wq,Wk,Wv}^T + bias ----
        int bx   = blockIdx.x;
        int m0   = (bx % 188) * 64;
        int n0   = (bx / 188) * 64;      // output col in [0,768)
        int wave = threadIdx.x >> 6;
        int lane = threadIdx.x & 63;
        int r16  = lane & 15;
        int quad = lane >> 4;

        int sel = n0 >> 8;               // 0=Q, 1=K, 2=V
        int jb  = n0 & 255;
        const float* wsrc = (sel == 0) ? wq : (sel == 1) ? wk : wv;
        const float* bias = (sel == 0) ? bq : (sel == 1) ? bk : bv;

        int arow = m0 + wave * 16 + r16;
        int rr   = arow < MTOT ? arow : MTOT - 1;
        const float* asrc = (rr < NROW) ? (e1 + (size_t)rr * HID)
                                        : (e2 + (size_t)(rr - NROW) * HID);

        // preload all 8 A fragments (f32 -> bf16) once; reused in both stages
        bf16x8 afr[8];
#pragma unroll
        for (int k8 = 0; k8 < 8; ++k8)
            afr[k8] = cvt8(asrc + k8 * 32 + quad * 8);

        f32x4 acc0 = {0,0,0,0}, acc1 = {0,0,0,0}, acc2 = {0,0,0,0}, acc3 = {0,0,0,0};

        // ---- stage 1: weight rows jb+0 .. jb+31 -> acc0 (rows 0-15), acc1 (16-31)
        for (int i = threadIdx.x; i < 32 * 64; i += 256) {
            int row = i >> 6;            // 0..31
            int kq  = (i & 63) * 4;      // 0..252
            f32x4 w4 = *(const f32x4*)(wsrc + (size_t)(jb + row) * HID + kq);
            bf16x4 b4;
#pragma unroll
            for (int z = 0; z < 4; ++z) b4[z] = (bf16_t)w4[z];
            *(bf16x4*)(&lds_w[row * WSTR + kq]) = b4;
        }
        __syncthreads();
#pragma unroll
        for (int k8 = 0; k8 < 8; ++k8) {
            const bf16_t* b0 = lds_w + (size_t)r16 * WSTR + k8 * 32 + quad * 8;
            bf16x8 f0 = *(const bf16x8*)(b0);
            bf16x8 f1 = *(const bf16x8*)(b0 + 16 * WSTR);
            acc0 = __builtin_amdgcn_mfma_f32_16x16x32_bf16(afr[k8], f0, acc0, 0, 0, 0);
            acc1 = __builtin_amdgcn_mfma_f32_16x16x32_bf16(afr[k8], f1, acc1, 0, 0, 0);
        }
        __syncthreads();

        // ---- stage 2: weight rows jb+32 .. jb+63 -> acc2, acc3
        for (int i = threadIdx.x; i < 32 * 64; i += 256) {
            int row = i >> 6;
            int kq  = (i & 63) * 4;
            f32x4 w4 = *(const f32x4*)(wsrc + (size_t)(jb + 32 + row) * HID + kq);
            bf16x4 b4;
#pragma unroll
            for (int z = 0; z < 4; ++z) b4[z] = (bf16_t)w4[z];
            *(bf16x4*)(&lds_w[row * WSTR + kq]) = b4;
        }
        __syncthreads();
#pragma unroll
        for (int k8 = 0; k8 < 8; ++k8) {
            const bf16_t* b0 = lds_w + (size_t)r16 * WSTR + k8 * 32 + quad * 8;
            bf16x8 f2 = *(const bf16x8*)(b0);
            bf16x8 f3 = *(const bf16x8*)(b0 + 16 * WSTR);
            acc2 = __builtin_amdgcn_mfma_f32_16x16x32_bf16(afr[k8], f2, acc2, 0, 0, 0);
            acc3 = __builtin_amdgcn_mfma_f32_16x16x32_bf16(afr[k8], f3, acc3, 0, 0, 0);
        }

        f32x4 accs[4] = {acc0, acc1, acc2, acc3};
        bf16_t* dst = (sel == 0) ? Q : (sel == 1) ? Kf : V;
        int rbase = m0 + wave * 16 + quad * 4;
#pragma unroll
        for (int nt = 0; nt < 4; ++nt) {
            int j = jb + nt * 16 + r16;
            float bb = bias[j];
#pragma unroll
            for (int rg = 0; rg < 4; ++rg) {
                int r = rbase + rg;
                if (r < MTOT)
                    dst[(size_t)r * HID + j] = (bf16_t)(accs[nt][rg] + bb);
            }
        }
        return;
    }

    // ---- scan: 16 f32 elements (64 B) per lane, wave-aggregated ELL ----
    int lane = threadIdx.x & 63;
    int ch   = (blockIdx.x - PROJ_BLOCKS) * 256 + threadIdx.x;
    bool oob = (ch >= NCH16);
    int che  = oob ? (NCH16 - 1) : ch;

    unsigned int nzmask = 0;
    if (!oob) {
        const uint4* p4 = (const uint4*)((const unsigned int*)am + (size_t)che * 16);
        uint4 u0 = p4[0], u1 = p4[1], u2 = p4[2], u3 = p4[3];
        unsigned int any = u0.x | u0.y | u0.z | u0.w | u1.x | u1.y | u1.z | u1.w
                         | u2.x | u2.y | u2.z | u2.w | u3.x | u3.y | u3.z | u3.w;
        if (any) {
            unsigned int w[16] = {u0.x, u0.y, u0.z, u0.w, u1.x, u1.y, u1.z, u1.w,
                                  u2.x, u2.y, u2.z, u2.w, u3.x, u3.y, u3.z, u3.w};
#pragma unroll
            for (int p = 0; p < 16; ++p)
                if (w[p]) nzmask |= 1u << p;
        }
    }
    int n  = che / 375;              // row of this chunk
    int m0 = (che - n * 375) * 16;   // first column of this chunk
    int c  = __popc(nzmask);

    // wave-wide exclusive prefix of c
    int p = c;
#pragma unroll
    for (int off = 1; off < 64; off <<= 1) {
        int t = __shfl_up(p, off);
        if (lane >= off) p += t;
    }
    int excl  = p - c;
    int total = __shfl(p, 63);

    int nFirst = __shfl(n, 0);
    int nLast  = __shfl(n, 63);
    unsigned long long mb = __ballot(n == nLast);
    int s0  = __ffsll(mb) - 1;       // first lane of the nLast segment
    int pS0 = __shfl(excl, s0);

    int baseB = 0;
    if (lane == s0) {
        int totalB = total - pS0;
        if (totalB > 0) baseB = atomicAdd(rcur + nLast, totalB);
    }
    baseB = __shfl(baseB, s0);
    int baseA = 0;
    if (s0 > 0) {                    // wave straddles two rows
        if (lane == 0 && pS0 > 0) baseA = atomicAdd(rcur + nFirst, pS0);
        baseA = __shfl(baseA, 0);
    }

    int myOff = (n == nLast) ? (baseB + excl - pS0) : (baseA + excl);
    if (c) {
        int* dst = csr + (size_t)n * CAP;
        int w = 0;
#pragma unroll
        for (int pb = 0; pb < 16; ++pb) {
            if (nzmask & (1u << pb)) {
                int idx = myOff + (w++);
                if (idx < CAP) dst[idx] = m0 + pb;
            }
        }
    }
}

// ============ K2: Kbar + Vsum  ∥  CSC-from-CSR scatter =======================
// Blocks [0,3000): Kbar. [3000,3048): Vsum. [3048,6048): CSC.
__global__ __launch_bounds__(256)
void k2_aux(const bf16_t* __restrict__ Kf, const bf16_t* __restrict__ V,
            bf16_t* __restrict__ Kbar, float* __restrict__ Vsum,
            const int* __restrict__ rcnt, const int* __restrict__ csr,
            int* __restrict__ ccur, int* __restrict__ csc)
{
    int b = blockIdx.x;
    if (b < 3000) {                       // Kbar: 12000*64 outputs
        int id = b * 256 + threadIdx.x;
        int m = id >> 6, d = id & 63;
        const bf16_t* kr = Kf + (size_t)m * HID + d;
        Kbar[id] = (bf16_t)(0.25f * ((float)kr[0] + (float)kr[64] +
                                     (float)kr[128] + (float)kr[192]));
    } else if (b < 3048) {                // Vsum: 2 graphs x 24 segments of 250
        int idx = b - 3000;
        int g = idx / 24;
        int seg = idx - g * 24;
        int j = threadIdx.x;
        const bf16_t* base = V + ((size_t)(g * NROW + seg * 250)) * HID + j;
        float s = 0.f;
        for (int m = 0; m < 250; ++m) s += (float)base[(size_t)m * HID];
        atomicAdd(Vsum + g * HID + j, s);
    } else {                              // CSC scatter
        int tid = (b - 3048) * 256 + threadIdx.x;   // n*CAP + j
        int n = tid >> 7, j = tid & (CAP - 1);
        if (n >= NROW) return;
        int cnt = rcnt[n]; if (cnt > CAP) cnt = CAP;
        if (j >= cnt) return;
        int m = csr[(size_t)n * CAP + j];
        int slot = atomicAdd(ccur + m, 1);
        if (slot < CAP) csc[(size_t)m * CAP + slot] = n;
    }
}

// ---------------- sparse-corrected attention (both directions) ---------------
// Exact softmax over 6000 kv entries: masked-out entries share weight e^-M/Z.
// Phase 1 on MFMA: scores = Kbar[rows]·q^T, A-fragments gathered directly from
// global (16B/lane, native A layout), B = q row (bf16, LDS), heads in C cols.
__global__ __launch_bounds__(256)
void attn_kernel(const bf16_t* __restrict__ Q, const bf16_t* __restrict__ Kbar,
                 const bf16_t* __restrict__ V, const float* __restrict__ Vsum,
                 const int* __restrict__ rcnt, const int* __restrict__ ccnt,
                 const int* __restrict__ csr, const int* __restrict__ csc,
                 bf16_t* __restrict__ att)
{
    __shared__ __align__(16) bf16_t qsb[HID];      // 0.5 KB, q row in bf16
    __shared__ int   ml[CAP];                      // 0.5 KB
    __shared__ float sc[CAP * 5];                  // 2.5 KB, [j][head] stride 5
    __shared__ float w0s[NHEAD];
    __shared__ float red[4 * HID];                 // 4 KB cross-wave reduction

    int dir = blockIdx.y;
    int n   = blockIdx.x;
    int t   = threadIdx.x;
    int wave = t >> 6, lane = t & 63;

    size_t qrow = (size_t)(dir ? NROW + n : n);
    const bf16_t* kb_base = Kbar + (dir ? 0 : (size_t)NROW * HD);
    const bf16_t* v_base  = V    + (dir ? 0 : (size_t)NROW * HID);
    const float*  vs      = Vsum + (dir ? 0 : HID);
    const int*    lst     = (dir ? csc : csr) + (size_t)n * CAP;
    int cnt = (dir ? ccnt : rcnt)[n];
    if (cnt > CAP) cnt = CAP;

    qsb[t] = Q[qrow * HID + t];
    for (int j = t; j < cnt; j += 256) ml[j] = lst[j];
    __syncthreads();

    int m16  = lane & 15;
    int quad = lane >> 4;

    // phase 1 (MFMA): per 16-j tile, scores[j][head] = SCALE * Kbar[mj]·q_head
    {
        bf16x8 b0, b1;
        if (m16 < NHEAD) {
            b0 = *(const bf16x8*)(qsb + m16 * HD + 0  + quad * 8);
            b1 = *(const bf16x8*)(qsb + m16 * HD + 32 + quad * 8);
        } else {
            b0 = (bf16x8)(bf16_t)0.f;
            b1 = (bf16x8)(bf16_t)0.f;
        }
        for (int jt = wave; jt * 16 < cnt; jt += 4) {
            int j  = jt * 16 + m16;
            int jj = j < cnt ? j : cnt - 1;           // clamp (cnt>0 here)
            int row = ml[jj];
            const bf16_t* ap = kb_base + (size_t)row * HD + quad * 8;
            bf16x8 a0 = *(const bf16x8*)(ap);
            bf16x8 a1 = *(const bf16x8*)(ap + 32);
            f32x4 acc = {0, 0, 0, 0};
            acc = __builtin_amdgcn_mfma_f32_16x16x32_bf16(a0, b0, acc, 0, 0, 0);
            acc = __builtin_amdgcn_mfma_f32_16x16x32_bf16(a1, b1, acc, 0, 0, 0);
            // C layout: col = lane&15 (head), row = quad*4 + rg (j within tile)
            if (m16 < NHEAD) {
#pragma unroll
                for (int rg = 0; rg < 4; ++rg) {
                    int jw = jt * 16 + quad * 4 + rg;
                    if (jw < cnt) sc[jw * 5 + m16] = acc[rg] * ATT_SCALE;
                }
            }
        }
    }
    __syncthreads();

    // phase 2: per-head exact softmax stats; wave `head` owns head `head`
    {
        int head = wave;
        float M = 0.0f;              // zero-score baseline always present
        for (int j = lane; j < cnt; j += 64) M = fmaxf(M, sc[j * 5 + head]);
        for (int off = 32; off; off >>= 1) M = fmaxf(M, __shfl_xor(M, off));
        float e0 = __expf(-M);
        float e[2]; int k = 0;
        float S = 0.f;
        for (int j = lane; j < cnt; j += 64, ++k) { e[k] = __expf(sc[j * 5 + head] - M); S += e[k]; }
        for (int off = 32; off; off >>= 1) S += __shfl_xor(S, off);
        float Z = S + (float)(NROW - cnt) * e0;
        float invZ = 1.0f / Z;
        k = 0;
        for (int j = lane; j < cnt; j += 64, ++k) sc[j * 5 + head] = (e[k] - e0) * invZ;
        if (lane == 0) w0s[head] = e0 * invZ;
    }
    __syncthreads();

    // phase 3: wave w handles j = w, w+4, ...; lane covers (h3, 4 dims).
    // 4-deep unroll keeps 4 V-row gathers in flight (L2-latency bound).
    int h3 = lane >> 4;
    int dq = lane & 15;
    int colb = h3 * HD + dq * 4;
    float a0 = 0.f, a1 = 0.f, a2 = 0.f, a3 = 0.f;
    {
        int j = wave;
        for (; j + 12 < cnt; j += 16) {
            int   m0 = ml[j];            int   m1 = ml[j + 4];
            int   m2 = ml[j + 8];        int   m3 = ml[j + 12];
            float c0 = sc[j * 5 + h3];   float c1 = sc[(j + 4) * 5 + h3];
            float c2 = sc[(j + 8) * 5 + h3]; float c3 = sc[(j + 12) * 5 + h3];
            bf16x4 r0 = *(const bf16x4*)(v_base + (size_t)m0 * HID + colb);
            bf16x4 r1 = *(const bf16x4*)(v_base + (size_t)m1 * HID + colb);
            bf16x4 r2 = *(const bf16x4*)(v_base + (size_t)m2 * HID + colb);
            bf16x4 r3 = *(const bf16x4*)(v_base + (size_t)m3 * HID + colb);
            a0 += c0 * (float)r0[0] + c1 * (float)r1[0] + c2 * (float)r2[0] + c3 * (float)r3[0];
            a1 += c0 * (float)r0[1] + c1 * (float)r1[1] + c2 * (float)r2[1] + c3 * (float)r3[1];
            a2 += c0 * (float)r0[2] + c1 * (float)r1[2] + c2 * (float)r2[2] + c3 * (float)r3[2];
            a3 += c0 * (float)r0[3] + c1 * (float)r1[3] + c2 * (float)r2[3] + c3 * (float)r3[3];
        }
        for (; j < cnt; j += 4) {
            int   m0 = ml[j];
            float c0 = sc[j * 5 + h3];
            bf16x4 r0 = *(const bf16x4*)(v_base + (size_t)m0 * HID + colb);
            a0 += c0 * (float)r0[0];
            a1 += c0 * (float)r0[1];
            a2 += c0 * (float)r0[2];
            a3 += c0 * (float)r0[3];
        }
    }
    red[wave * 256 + colb + 0] = a0;
    red[wave * 256 + colb + 1] = a1;
    red[wave * 256 + colb + 2] = a2;
    red[wave * 256 + colb + 3] = a3;
    __syncthreads();
    float tot = red[t] + red[256 + t] + red[512 + t] + red[768 + t]
              + w0s[t >> 6] * vs[t];
    att[qrow * HID + t] = (bf16_t)tot;
}

// ---------------- final projection + residual (self-staged Wo, f32 out) ------
__global__ __launch_bounds__(256)
void proj_out_kernel(const bf16_t* __restrict__ att, const float* __restrict__ wo,
                     const float* __restrict__ bo,
                     const float* __restrict__ e1, const float* __restrict__ e2,
                     float* __restrict__ out)
{
    __shared__ bf16_t lds_w[64 * WSTR];            // 33 KB (752 blocks: no occupancy issue)

    int m0   = blockIdx.x * 64;
    int n0   = blockIdx.y * 64;      // in [0,256)
    int wave = threadIdx.x >> 6;
    int lane = threadIdx.x & 63;
    int r16  = lane & 15;
    int quad = lane >> 4;

    // stage Wo rows n0..n0+63 f32 -> bf16 LDS
    for (int i = threadIdx.x; i < 64 * 64; i += 256) {
        int row = i >> 6;
        int kq  = (i & 63) * 4;
        f32x4 w4 = *(const f32x4*)(wo + (size_t)(n0 + row) * HID + kq);
        bf16x4 b4;
#pragma unroll
        for (int z = 0; z < 4; ++z) b4[z] = (bf16_t)w4[z];
        *(bf16x4*)(&lds_w[row * WSTR + kq]) = b4;
    }
    __syncthreads();

    int arow = m0 + wave * 16 + r16;
    int rr   = arow < MTOT ? arow : MTOT - 1;
    const bf16_t* asrc = att + (size_t)rr * HID;

    f32x4 acc0 = {0,0,0,0}, acc1 = {0,0,0,0}, acc2 = {0,0,0,0}, acc3 = {0,0,0,0};
#pragma unroll
    for (int kk = 0; kk < HID; kk += 32) {
        bf16x8 a = *(const bf16x8*)(asrc + kk + quad * 8);
        const bf16_t* b0 = lds_w + (size_t)r16 * WSTR + kk + quad * 8;
        bf16x8 f0 = *(const bf16x8*)(b0);
        bf16x8 f1 = *(const bf16x8*)(b0 + 16 * WSTR);
        bf16x8 f2 = *(const bf16x8*)(b0 + 32 * WSTR);
        bf16x8 f3 = *(const bf16x8*)(b0 + 48 * WSTR);
        acc0 = __builtin_amdgcn_mfma_f32_16x16x32_bf16(a, f0, acc0, 0, 0, 0);
        acc1 = __builtin_amdgcn_mfma_f32_16x16x32_bf16(a, f1, acc1, 0, 0, 0);
        acc2 = __builtin_amdgcn_mfma_f32_16x16x32_bf16(a, f2, acc2, 0, 0, 0);
        acc3 = __builtin_amdgcn_mfma_f32_16x16x32_bf16(a, f3, acc3, 0, 0, 0);
    }
    f32x4 accs[4] = {acc0, acc1, acc2, acc3};
    int rbase = m0 + wave * 16 + quad * 4;
#pragma unroll
    for (int nt = 0; nt < 4; ++nt) {
        int j = n0 + nt * 16 + r16;
        float bb = bo[j];
#pragma unroll
        for (int rg = 0; rg < 4; ++rg) {
            int r = rbase + rg;
            if (r < MTOT) {
                const float* emb = (r < NROW) ? (e1 + (size_t)r * HID)
                                              : (e2 + (size_t)(r - NROW) * HID);
                float v = accs[nt][rg] + bb + emb[j];
                out[(size_t)r * HID + j] = v;        // f32 out; concat row r -> r*256
            }
        }
    }
}

// ---------------- host launcher ----------------------------------------------
extern "C" void kernel_launch(void* const* d_in, const int* in_sizes, int n_in,
                              void* d_out, int out_size, void* d_ws, size_t ws_size,
                              hipStream_t stream)
{
    const float* e1 = (const float*)d_in[0];
    const float* e2 = (const float*)d_in[1];
    const float* am = (const float*)d_in[2];
    const float* wq = (const float*)d_in[3];
    const float* bq = (const float*)d_in[4];
    const float* wk = (const float*)d_in[5];
    const float* bk = (const float*)d_in[6];
    const float* wv = (const float*)d_in[7];
    const float* bv = (const float*)d_in[8];
    const float* wo = (const float*)d_in[9];
    const float* bo = (const float*)d_in[10];
    float* out = (float*)d_out;

    size_t off = 0;
    char* base = (char*)d_ws;
    auto alloc = [&](size_t bytes) -> void* {
        void* p = base + off;
        off += (bytes + 255) & ~(size_t)255;
        return p;
    };
    bf16_t* Q    = (bf16_t*)alloc((size_t)MTOT * HID * 2);
    bf16_t* Kf   = (bf16_t*)alloc((size_t)MTOT * HID * 2);
    bf16_t* V    = (bf16_t*)alloc((size_t)MTOT * HID * 2);
    bf16_t* Kbar = (bf16_t*)alloc((size_t)MTOT * HD * 2);
    bf16_t* att  = (bf16_t*)alloc((size_t)MTOT * HID * 2);
    int*    csr  = (int*)   alloc((size_t)NROW * CAP * 4);
    int*    csc  = (int*)   alloc((size_t)NROW * CAP * 4);
    // zeroed region: rcur | ccur | Vsum (contiguous)
    int*    rcur = (int*)   alloc(NROW * 4);
    int*    ccur = (int*)   alloc(NROW * 4);
    float*  Vsum = (float*) alloc(2 * HID * 4);

    size_t zero_bytes = (size_t)((char*)Vsum - (char*)rcur) + 2 * HID * 4;
    hipMemsetAsync(rcur, 0, zero_bytes, stream);

    // K1: QKV projection (2-stage 16.9 KB LDS) ∥ 16-wide align scan
    k1_proj_scan<<<PROJ_BLOCKS + SCAN_BLOCKS, 256, 0, stream>>>(
        e1, e2, wq, wk, wv, bq, bk, bv, Q, Kf, V, am, rcur, csr);

    // K2: Kbar + Vsum ∥ CSC scatter (all depend only on K1)
    k2_aux<<<6048, 256, 0, stream>>>(Kf, V, Kbar, Vsum, rcur, csr, ccur, csc);

    // K3: attention, both directions
    attn_kernel<<<dim3(NROW, 2), 256, 0, stream>>>(
        Q, Kbar, V, Vsum, rcur, ccur, csr, csc, att);

    // K4: final projection + residual (self-staged Wo, f32 output)
    proj_out_kernel<<<dim3(188, 4), 256, 0, stream>>>(att, wo, bo, e1, e2, out);
}